// Round 3
// baseline (1238.860 us; speedup 1.0000x reference)
//
#include <hip/hip_runtime.h>
#include <math.h>

#define KNN 20
#define NPTS 4096
#define BATCH 8
#define P_TOT (BATCH * NPTS)       // 32768
#define QPW 8                      // queries per wave
#define WPB 8                      // waves per block (512 threads)
#define QPB (QPW * WPB)            // 64 queries per block
#define NBLK (P_TOT / QPB)         // 512 blocks
#define BPB (NPTS / QPB)           // 64 blocks per batch
#define NWAVE (NBLK * WPB)         // 4096 waves
#define BN_EPS 1e-5
#define NEG_SLOPE 0.2f

// float-offsets into ws
#define FO_CLOUD 0                 // 32768 float4 = 131072 floats
#define FO_PART  131072            // 4096 wave-partials x 128 floats = 524288
#define FO_AB    655360            // 128 floats (a, shift)
#define FO_W2    655488            // 448 floats (folded W + bias)
#define FO_BIG   655936            // rawmin (2097152 f) or idx (655360 i)

__device__ __forceinline__ unsigned int fkey(float f) {
    unsigned int u = __float_as_uint(f);
    return (u & 0x80000000u) ? ~u : (u | 0x80000000u);
}
__device__ __forceinline__ unsigned long long umin64(unsigned long long a, unsigned long long b) {
    return a < b ? a : b;
}

// ---------- kernel 1: pack cloud as float4 (x,y,z,|p|^2) ----------
__global__ __launch_bounds__(256) void pack_kernel(const float* __restrict__ pcd,
                                                   float4* __restrict__ cloud) {
    int i = blockIdx.x * 256 + threadIdx.x;
    float x = pcd[3 * i], y = pcd[3 * i + 1], z = pcd[3 * i + 2];
    float sq = __fadd_rn(__fadd_rn(__fmul_rn(x, x), __fmul_rn(y, y)), __fmul_rn(z, z));
    cloud[i] = make_float4(x, y, z, sq);
}

// distance, bit-exact vs reference (validated in R1/R2)
#define DIST(C) ({ \
    float dot_ = __fadd_rn(__fadd_rn(__fmul_rn(qx, (C).x), __fmul_rn(qy, (C).y)), \
                           __fmul_rn(qz, (C).z)); \
    __fsub_rn(__fadd_rn(qs, (C).w), __fmul_rn(2.0f, dot_)); })

// full recompute of group G's top-2 from LDS, excluding extracted slots (static G)
#define RECOMP(G) { \
    float m1 = INFINITY, m2 = INFINITY; int s1 = 0, s2 = 0; \
    _Pragma("unroll") \
    for (int e = 0; e < 8; ++e) { \
        const int sl = (G) * 8 + e; \
        const float4 C = cl[sl * 64 + lane]; \
        float dd = DIST(C); \
        if ((mask >> sl) & 1ull) dd = INFINITY; \
        if (dd < m1) { m2 = m1; s2 = s1; m1 = dd; s1 = sl; } \
        else if (dd < m2) { m2 = dd; s2 = sl; } \
    } \
    gv1[G] = m1; gs1[G] = s1; gv2[G] = m2; gs2[G] = s2; }

#define PROMOTE(G) { \
    if (gv2[G] < INFINITY) { gv1[G] = gv2[G]; gs1[G] = gs2[G]; gv2[G] = INFINITY; } \
    else { RECOMP(G) } }

// ---------- kernel 2: fused kNN + edge-MLP stats + raw max/min ----------
template <bool FAST>
__global__ __launch_bounds__(512, 4) void knn_kernel(const float4* __restrict__ cloud,
                                                     const float* __restrict__ W,
                                                     const float* __restrict__ bias,
                                                     float* __restrict__ partials,
                                                     float* __restrict__ rawmax,
                                                     float* __restrict__ rawmin,
                                                     int* __restrict__ idxo) {
    __shared__ float4 cl[NPTS];    // 64 KB
    const int t = threadIdx.x;
    const int wave = t >> 6, lane = t & 63;
    const int bidx = blockIdx.x;
    const int batch = bidx / BPB;
    const int gbase = batch * NPTS;

#pragma unroll
    for (int it = 0; it < NPTS / 512; ++it)
        cl[it * 512 + t] = cloud[gbase + it * 512 + t];
    __syncthreads();

    const float wc0 = W[lane], wc1 = W[64 + lane], wc2 = W[128 + lane];
    const float wc3 = W[192 + lane], wc4 = W[256 + lane], wc5 = W[320 + lane];
    const float bb = bias[lane];
    float se = 0.f, sqs = 0.f;

    for (int qi = 0; qi < QPW; ++qi) {
        const int q = (bidx % BPB) * QPB + wave * QPW + qi;  // in-batch query id
        const int gq = gbase + q;
        const float4 Q = cl[q];
        const float qx = Q.x, qy = Q.y, qz = Q.z, qs = Q.w;

        // ---- distance pass: per-lane 8 groups x 8 candidates, keep top-2/group ----
        float gv1[8], gv2[8];
        int gs1[8], gs2[8];
#pragma unroll
        for (int g = 0; g < 8; ++g) { gv1[g] = INFINITY; gv2[g] = INFINITY; gs1[g] = 0; gs2[g] = 0; }
#pragma unroll
        for (int j = 0; j < 64; ++j) {     // j = slot; candidate m = j*64+lane
            const float4 C = cl[j * 64 + lane];
            const float dd = DIST(C);
            const int g = j >> 3;          // compile-time (unrolled)
            if (dd < gv1[g]) { gv2[g] = gv1[g]; gs2[g] = gs1[g]; gv1[g] = dd; gs1[g] = j; }
            else if (dd < gv2[g]) { gv2[g] = dd; gs2[g] = j; }
        }
        // lane-min key
        float bv = gv1[0]; int bs = gs1[0];
#pragma unroll
        for (int g = 1; g < 8; ++g) if (gv1[g] < bv) { bv = gv1[g]; bs = gs1[g]; }
        unsigned long long dk = ((unsigned long long)fkey(bv) << 32) |
                                (unsigned int)(bs * 64 + lane);
        unsigned long long mask = 0ull;
        float hmax = -INFINITY, hmin = INFINITY;

#pragma unroll 1
        for (int p = 0; p < KNN; ++p) {
            // wave-wide u64 min: winner (dist,idx) known to all lanes
            unsigned long long k = dk;
#pragma unroll
            for (int off = 32; off; off >>= 1) k = umin64(k, __shfl_xor(k, off));
            const int m = (int)(k & 0xFFFFFFFFull);      // in-batch neighbor id

            if (!FAST) { if (lane == 0) idxo[gq * KNN + p] = m; }

            // ---- fused channel phase (lane = channel), wave-uniform broadcast ----
            const float4 C = cl[m];
            float raw = bb;
            raw = fmaf(wc0, C.x, raw);
            raw = fmaf(wc1, C.y, raw);
            raw = fmaf(wc2, C.z, raw);
            raw = fmaf(wc3, qx - C.x, raw);
            raw = fmaf(wc4, qy - C.y, raw);
            raw = fmaf(wc5, qz - C.z, raw);
            se += raw;
            sqs = fmaf(raw, raw, sqs);
            hmax = fmaxf(hmax, raw);
            hmin = fminf(hmin, raw);

            // ---- owner-lane repair: promote min2, or rare group recompute ----
            if ((m & 63) == lane) {
                const int slot = m >> 6;         // wave-uniform
                mask |= (1ull << slot);
                switch (slot >> 3) {
                    case 0: PROMOTE(0); break;
                    case 1: PROMOTE(1); break;
                    case 2: PROMOTE(2); break;
                    case 3: PROMOTE(3); break;
                    case 4: PROMOTE(4); break;
                    case 5: PROMOTE(5); break;
                    case 6: PROMOTE(6); break;
                    default: PROMOTE(7); break;
                }
                float nv = gv1[0]; int ns = gs1[0];
#pragma unroll
                for (int g2 = 1; g2 < 8; ++g2) if (gv1[g2] < nv) { nv = gv1[g2]; ns = gs1[g2]; }
                dk = ((unsigned long long)fkey(nv) << 32) | (unsigned int)(ns * 64 + lane);
            }
        }

        if (FAST) {
            rawmax[gq * 64 + lane] = hmax;
            rawmin[gq * 64 + lane] = hmin;
        }
    }

    partials[(bidx * WPB + wave) * 128 + lane] = se;
    partials[(bidx * WPB + wave) * 128 + 64 + lane] = sqs;
}

// ---------- kernel 3: reduce stats, finalize BN, fold affine ----------
__global__ void finalize_kernel(const float* __restrict__ partials,
                                const float* __restrict__ W,
                                const float* __restrict__ bias,
                                const float* __restrict__ gamma,
                                const float* __restrict__ beta,
                                float* __restrict__ ab,
                                float* __restrict__ w2) {
    __shared__ double red[8][64];
    const int t = threadIdx.x, c = t & 63, part = t >> 6;  // 256 threads
    double s = 0.0, q = 0.0;
    for (int i = part; i < NWAVE; i += 4) {
        s += (double)partials[i * 128 + c];
        q += (double)partials[i * 128 + 64 + c];
    }
    red[part][c] = s;
    red[4 + part][c] = q;
    __syncthreads();
    if (t < 64) {
        double ss = red[0][t] + red[1][t] + red[2][t] + red[3][t];
        double qq = red[4][t] + red[5][t] + red[6][t] + red[7][t];
        const double cnt = (double)P_TOT * KNN;
        double mean = ss / cnt;
        double var = qq / cnt - mean * mean;
        double a = (double)gamma[t] / sqrt(var + BN_EPS);
        float af = (float)a;
        float sh = (float)((double)beta[t] - mean * a);
        ab[t] = af;
        ab[64 + t] = sh;
#pragma unroll
        for (int f = 0; f < 6; ++f) w2[f * 64 + t] = W[f * 64 + t] * af;
        w2[384 + t] = fmaf(bias[t], af, sh);
    }
}

// ---------- kernel 4a (fast): elementwise BN+LeakyReLU on raw max/min ----------
__global__ __launch_bounds__(256) void final_kernel(const float* __restrict__ ab,
                                                    const float* __restrict__ rawmin,
                                                    float* __restrict__ out) {
    int i = blockIdx.x * 256 + threadIdx.x;
    int c = i & 63;
    float a = ab[c], sh = ab[64 + c];
    float va = fmaf(a, out[i], sh);       // out currently holds rawmax
    float vb = fmaf(a, rawmin[i], sh);
    va = va >= 0.f ? va : NEG_SLOPE * va;
    vb = vb >= 0.f ? vb : NEG_SLOPE * vb;
    out[i] = fmaxf(va, vb);               // monotone: covers a>=0 and a<0
}

// ---------- kernel 4b (fallback): gather + folded MLP + maxpool ----------
__global__ __launch_bounds__(256) void out_kernel(const float4* __restrict__ cloud,
                                                  const int* __restrict__ idxo,
                                                  const float* __restrict__ w2,
                                                  float* __restrict__ out) {
    const int t = threadIdx.x, c = t & 63;
    const int gp = blockIdx.x * 4 + (t >> 6);
    const int gb = gp & ~(NPTS - 1);
    const float wc0 = w2[c], wc1 = w2[64 + c], wc2 = w2[128 + c];
    const float wc3 = w2[192 + c], wc4 = w2[256 + c], wc5 = w2[320 + c];
    const float bc = w2[384 + c];
    const float4 Q = cloud[gp];
    float vmax = -INFINITY;
    for (int k = 0; k < KNN; ++k) {
        const int m = idxo[gp * KNN + k];
        const float4 C = cloud[gb + m];
        float h = bc;
        h = fmaf(wc0, C.x, h);
        h = fmaf(wc1, C.y, h);
        h = fmaf(wc2, C.z, h);
        h = fmaf(wc3, Q.x - C.x, h);
        h = fmaf(wc4, Q.y - C.y, h);
        h = fmaf(wc5, Q.z - C.z, h);
        h = h >= 0.f ? h : NEG_SLOPE * h;
        vmax = fmaxf(vmax, h);
    }
    out[gp * 64 + c] = vmax;
}

extern "C" void kernel_launch(void* const* d_in, const int* in_sizes, int n_in,
                              void* d_out, int out_size, void* d_ws, size_t ws_size,
                              hipStream_t stream) {
    const float* pcd   = (const float*)d_in[0];
    const float* W     = (const float*)d_in[1];
    const float* bias  = (const float*)d_in[2];
    const float* gamma = (const float*)d_in[3];
    const float* beta  = (const float*)d_in[4];

    float* wsf = (float*)d_ws;
    float4* cloud   = (float4*)(wsf + FO_CLOUD);
    float* partials = wsf + FO_PART;
    float* ab       = wsf + FO_AB;
    float* w2       = wsf + FO_W2;
    float* big      = wsf + FO_BIG;
    float* out      = (float*)d_out;

    const size_t need_fast = (size_t)FO_BIG * 4 + (size_t)P_TOT * 64 * 4 + 1024;
    const bool fast = ws_size >= need_fast;

    pack_kernel<<<P_TOT / 256, 256, 0, stream>>>(pcd, cloud);
    if (fast) {
        knn_kernel<true><<<NBLK, 512, 0, stream>>>(cloud, W, bias, partials, out, big, nullptr);
        finalize_kernel<<<1, 256, 0, stream>>>(partials, W, bias, gamma, beta, ab, w2);
        final_kernel<<<(P_TOT * 64) / 256, 256, 0, stream>>>(ab, big, out);
    } else {
        knn_kernel<false><<<NBLK, 512, 0, stream>>>(cloud, W, bias, partials, nullptr, nullptr, (int*)big);
        finalize_kernel<<<1, 256, 0, stream>>>(partials, W, bias, gamma, beta, ab, w2);
        out_kernel<<<P_TOT / 4, 256, 0, stream>>>(cloud, (int*)big, w2, out);
    }
}

// Round 4
// 217.405 us; speedup vs baseline: 5.6984x; 5.6984x over previous
//
#include <hip/hip_runtime.h>
#include <math.h>

#define KNN 20
#define NPTS 4096
#define BATCH 8
#define P_TOT (BATCH * NPTS)       // 32768
#define QPW 8                      // queries per wave
#define WPB 8                      // waves per block (512 threads)
#define QPB (QPW * WPB)            // 64 queries per block
#define NBLK (P_TOT / QPB)         // 512 blocks
#define BPB (NPTS / QPB)           // 64 blocks per batch
#define BN_EPS 1e-5
#define NEG_SLOPE 0.2f

// float-offsets into ws
#define FO_CLOUD 0                 // 32768 float4 = 131072 floats
#define FO_PART  131072            // 512 x 128 block partials
#define FO_PART2 196608            // 64 x 128 stage-2 partials
#define FO_AB    655360            // 128 floats (a, shift)
#define FO_W2    655488            // 448 floats (folded W + bias)
#define FO_BIG   655936            // rawmin (2097152 f) or idx (655360 i)

// ---------- kernel 1: pack cloud as float4 (x,y,z,|p|^2) ----------
__global__ __launch_bounds__(256) void pack_kernel(const float* __restrict__ pcd,
                                                   float4* __restrict__ cloud) {
    int i = blockIdx.x * 256 + threadIdx.x;
    float x = pcd[3 * i], y = pcd[3 * i + 1], z = pcd[3 * i + 2];
    float sq = __fadd_rn(__fadd_rn(__fmul_rn(x, x), __fmul_rn(y, y)), __fmul_rn(z, z));
    cloud[i] = make_float4(x, y, z, sq);
}

// distance, bit-exact vs reference (validated R1-R3):
// 2*dot is exact (pow2 scale), so fmaf(-2,dot,s) == __fsub_rn(s, 2*dot)
#define DIST(C) ({ \
    float dot_ = __fadd_rn(__fadd_rn(__fmul_rn(qx, (C).x), __fmul_rn(qy, (C).y)), \
                           __fmul_rn(qz, (C).z)); \
    fmaf(-2.0f, dot_, __fadd_rn(qs, (C).w)); })

// full recompute of group G's top-2 from LDS, excluding extracted slots (static G)
#define RECOMP(G) { \
    float m1 = INFINITY, m2 = INFINITY; int s1 = 0, s2 = 0; \
    _Pragma("unroll") \
    for (int e = 0; e < 8; ++e) { \
        const int sl = (G) * 8 + e; \
        const float4 C = cl[sl * 64 + lane]; \
        float dd = DIST(C); \
        if ((mask >> sl) & 1ull) dd = INFINITY; \
        if (dd < m1) { m2 = m1; s2 = s1; m1 = dd; s1 = sl; } \
        else if (dd < m2) { m2 = dd; s2 = sl; } \
    } \
    gv1[G] = m1; gs1[G] = s1; gv2[G] = m2; gs2[G] = s2; }

#define PROMOTE(G) { \
    if (gv2[G] < INFINITY) { gv1[G] = gv2[G]; gs1[G] = gs2[G]; gv2[G] = INFINITY; } \
    else { RECOMP(G) } }

// ---------- kernel 2: fused kNN + folded edge-MLP stats + raw max/min ----------
template <bool FAST>
__global__ __launch_bounds__(512, 2) void knn_kernel(const float4* __restrict__ cloud,
                                                     const float* __restrict__ W,
                                                     const float* __restrict__ bias,
                                                     float* __restrict__ partials,
                                                     float* __restrict__ rawmax,
                                                     float* __restrict__ rawmin,
                                                     int* __restrict__ idxo) {
    __shared__ float4 cl[NPTS];    // 64 KB
    const int t = threadIdx.x;
    const int wave = t >> 6, lane = t & 63;
    const int bidx = blockIdx.x;
    const int batch = bidx / BPB;
    const int gbase = batch * NPTS;

#pragma unroll
    for (int it = 0; it < NPTS / 512; ++it)
        cl[it * 512 + t] = cloud[gbase + it * 512 + t];
    __syncthreads();

    // folded MLP: raw = qoff + wd0*Cx + wd1*Cy + wd2*Cz
    const float wc3 = W[192 + lane], wc4 = W[256 + lane], wc5 = W[320 + lane];
    const float wd0 = W[lane] - wc3, wd1 = W[64 + lane] - wc4, wd2 = W[128 + lane] - wc5;
    const float bb = bias[lane];
    float se = 0.f, sqs = 0.f;

#pragma unroll 1
    for (int qi = 0; qi < QPW; ++qi) {
        const int q = (bidx % BPB) * QPB + wave * QPW + qi;  // in-batch query id
        const int gq = gbase + q;
        const float4 Q = cl[q];
        const float qx = Q.x, qy = Q.y, qz = Q.z, qs = Q.w;
        const float qoff = fmaf(wc3, qx, fmaf(wc4, qy, fmaf(wc5, qz, bb)));

        // ---- distance pass: 8 groups x 8 candidates per lane, top-2 per group ----
        float gv1[8], gv2[8];
        int gs1[8], gs2[8];
#pragma unroll
        for (int g = 0; g < 8; ++g) { gv1[g] = INFINITY; gv2[g] = INFINITY; gs1[g] = 0; gs2[g] = 0; }
#pragma unroll
        for (int g = 0; g < 8; ++g) {
#pragma unroll
            for (int e = 0; e < 8; ++e) {
                const int j = g * 8 + e;                 // compile-time slot
                const float4 C = cl[j * 64 + lane];
                const float dd = DIST(C);
                const bool c1 = dd < gv1[g];
                const bool c2 = dd < gv2[g];
                gv2[g] = c1 ? gv1[g] : (c2 ? dd : gv2[g]);
                gs2[g] = c1 ? gs1[g] : (c2 ? j : gs2[g]);
                gv1[g] = c1 ? dd : gv1[g];
                gs1[g] = c1 ? j : gs1[g];
            }
            __builtin_amdgcn_sched_barrier(0);           // cap live loads at one group
        }
        float dmin = gv1[0]; int bs = gs1[0];
#pragma unroll
        for (int g = 1; g < 8; ++g) if (gv1[g] < dmin) { dmin = gv1[g]; bs = gs1[g]; }
        int mmin = bs * 64 + lane;
        unsigned long long mask = 0ull;
        float hmax = -INFINITY, hmin = INFINITY;

#pragma unroll 1
        for (int p = 0; p < KNN; ++p) {
            // wave-wide float min
            float gmin = dmin;
#pragma unroll
            for (int off = 32; off; off >>= 1) gmin = fminf(gmin, __shfl_xor(gmin, off));
            unsigned long long bal = __ballot(dmin == gmin);
            int win;
            if (__popcll(bal) > 1) {
                // exact distance tie across lanes: smallest global index (lax.top_k)
                int mv = (dmin == gmin) ? mmin : 0x7FFFFFFF;
#pragma unroll
                for (int off = 32; off; off >>= 1) mv = min(mv, __shfl_xor(mv, off));
                win = mv;
            } else {
                win = __shfl(mmin, __ffsll((unsigned long long)bal) - 1);
            }

            if (!FAST) { if (lane == 0) idxo[gq * KNN + p] = win; }

            // ---- fused channel phase (lane = channel), uniform broadcast ----
            const float4 C = cl[win];
            const float raw = fmaf(wd0, C.x, fmaf(wd1, C.y, fmaf(wd2, C.z, qoff)));
            se += raw;
            sqs = fmaf(raw, raw, sqs);
            hmax = fmaxf(hmax, raw);
            hmin = fminf(hmin, raw);

            // ---- owner-lane repair ----
            if ((win & 63) == lane) {
                const int slot = win >> 6;
                mask |= (1ull << slot);
                switch (slot >> 3) {
                    case 0: PROMOTE(0); break;
                    case 1: PROMOTE(1); break;
                    case 2: PROMOTE(2); break;
                    case 3: PROMOTE(3); break;
                    case 4: PROMOTE(4); break;
                    case 5: PROMOTE(5); break;
                    case 6: PROMOTE(6); break;
                    default: PROMOTE(7); break;
                }
                float nv = gv1[0]; int ns = gs1[0];
#pragma unroll
                for (int g2 = 1; g2 < 8; ++g2) if (gv1[g2] < nv) { nv = gv1[g2]; ns = gs1[g2]; }
                dmin = nv; mmin = ns * 64 + lane;
            }
        }

        if (FAST) {
            rawmax[gq * 64 + lane] = hmax;
            rawmin[gq * 64 + lane] = hmin;
        }
    }

    // ---- cross-wave stats reduce (reuse cl LDS) ----
    __syncthreads();
    float* sred = (float*)cl;
    sred[wave * 128 + lane] = se;
    sred[wave * 128 + 64 + lane] = sqs;
    __syncthreads();
    if (t < 128) {
        float s = 0.f;
#pragma unroll
        for (int w = 0; w < WPB; ++w) s += sred[w * 128 + t];
        partials[bidx * 128 + t] = s;
    }
}

// ---------- kernel 3a: reduce 512 block-partials -> 64 ----------
__global__ __launch_bounds__(128) void finA_kernel(const float* __restrict__ partials,
                                                   float* __restrict__ part2) {
    const int b = blockIdx.x, t = threadIdx.x;   // 64 blocks x 128 threads
    float s = 0.f;
#pragma unroll
    for (int i = 0; i < 8; ++i) s += partials[(b * 8 + i) * 128 + t];
    part2[b * 128 + t] = s;
}

// ---------- kernel 3b: finalize BN, fold affine ----------
__global__ __launch_bounds__(64) void finB_kernel(const float* __restrict__ part2,
                                                  const float* __restrict__ W,
                                                  const float* __restrict__ bias,
                                                  const float* __restrict__ gamma,
                                                  const float* __restrict__ beta,
                                                  float* __restrict__ ab,
                                                  float* __restrict__ w2) {
    const int c = threadIdx.x;   // 64 threads
    double s0 = 0.0, s1 = 0.0, q0 = 0.0, q1 = 0.0;
    for (int i = 0; i < 64; i += 2) {
        s0 += (double)part2[i * 128 + c];
        q0 += (double)part2[i * 128 + 64 + c];
        s1 += (double)part2[(i + 1) * 128 + c];
        q1 += (double)part2[(i + 1) * 128 + 64 + c];
    }
    const double cnt = (double)P_TOT * KNN;
    double mean = (s0 + s1) / cnt;
    double var = (q0 + q1) / cnt - mean * mean;
    double a = (double)gamma[c] / sqrt(var + BN_EPS);
    float af = (float)a;
    float sh = (float)((double)beta[c] - mean * a);
    ab[c] = af;
    ab[64 + c] = sh;
#pragma unroll
    for (int f = 0; f < 6; ++f) w2[f * 64 + c] = W[f * 64 + c] * af;
    w2[384 + c] = fmaf(bias[c], af, sh);
}

// ---------- kernel 4a (fast): elementwise BN+LeakyReLU on raw max/min ----------
__global__ __launch_bounds__(256) void final_kernel(const float* __restrict__ ab,
                                                    const float* __restrict__ rawmin,
                                                    float* __restrict__ out) {
    int i = blockIdx.x * 256 + threadIdx.x;
    int c = i & 63;
    float a = ab[c], sh = ab[64 + c];
    float va = fmaf(a, out[i], sh);       // out currently holds rawmax
    float vb = fmaf(a, rawmin[i], sh);
    va = va >= 0.f ? va : NEG_SLOPE * va;
    vb = vb >= 0.f ? vb : NEG_SLOPE * vb;
    out[i] = fmaxf(va, vb);               // monotone: covers a>=0 and a<0
}

// ---------- kernel 4b (fallback): gather + folded MLP + maxpool ----------
__global__ __launch_bounds__(256) void out_kernel(const float4* __restrict__ cloud,
                                                  const int* __restrict__ idxo,
                                                  const float* __restrict__ w2,
                                                  float* __restrict__ out) {
    const int t = threadIdx.x, c = t & 63;
    const int gp = blockIdx.x * 4 + (t >> 6);
    const int gb = gp & ~(NPTS - 1);
    const float wc0 = w2[c], wc1 = w2[64 + c], wc2 = w2[128 + c];
    const float wc3 = w2[192 + c], wc4 = w2[256 + c], wc5 = w2[320 + c];
    const float bc = w2[384 + c];
    const float4 Q = cloud[gp];
    float vmax = -INFINITY;
    for (int k = 0; k < KNN; ++k) {
        const int m = idxo[gp * KNN + k];
        const float4 C = cloud[gb + m];
        float h = bc;
        h = fmaf(wc0, C.x, h);
        h = fmaf(wc1, C.y, h);
        h = fmaf(wc2, C.z, h);
        h = fmaf(wc3, Q.x - C.x, h);
        h = fmaf(wc4, Q.y - C.y, h);
        h = fmaf(wc5, Q.z - C.z, h);
        h = h >= 0.f ? h : NEG_SLOPE * h;
        vmax = fmaxf(vmax, h);
    }
    out[gp * 64 + c] = vmax;
}

extern "C" void kernel_launch(void* const* d_in, const int* in_sizes, int n_in,
                              void* d_out, int out_size, void* d_ws, size_t ws_size,
                              hipStream_t stream) {
    const float* pcd   = (const float*)d_in[0];
    const float* W     = (const float*)d_in[1];
    const float* bias  = (const float*)d_in[2];
    const float* gamma = (const float*)d_in[3];
    const float* beta  = (const float*)d_in[4];

    float* wsf = (float*)d_ws;
    float4* cloud   = (float4*)(wsf + FO_CLOUD);
    float* partials = wsf + FO_PART;
    float* part2    = wsf + FO_PART2;
    float* ab       = wsf + FO_AB;
    float* w2       = wsf + FO_W2;
    float* big      = wsf + FO_BIG;
    float* out      = (float*)d_out;

    const size_t need_fast = (size_t)FO_BIG * 4 + (size_t)P_TOT * 64 * 4 + 1024;
    const bool fast = ws_size >= need_fast;

    pack_kernel<<<P_TOT / 256, 256, 0, stream>>>(pcd, cloud);
    if (fast) {
        knn_kernel<true><<<NBLK, 512, 0, stream>>>(cloud, W, bias, partials, out, big, nullptr);
        finA_kernel<<<64, 128, 0, stream>>>(partials, part2);
        finB_kernel<<<1, 64, 0, stream>>>(part2, W, bias, gamma, beta, ab, w2);
        final_kernel<<<(P_TOT * 64) / 256, 256, 0, stream>>>(ab, big, out);
    } else {
        knn_kernel<false><<<NBLK, 512, 0, stream>>>(cloud, W, bias, partials, nullptr, nullptr, (int*)big);
        finA_kernel<<<64, 128, 0, stream>>>(partials, part2);
        finB_kernel<<<1, 64, 0, stream>>>(part2, W, bias, gamma, beta, ab, w2);
        out_kernel<<<P_TOT / 4, 256, 0, stream>>>(cloud, (int*)big, w2, out);
    }
}